// Round 4
// baseline (967.735 us; speedup 1.0000x reference)
//
#include <hip/hip_runtime.h>

// Forward warp (bilinear splat), gather formulation, v3.
// im0 [B,C,H,W] f32, flow [B,H,W,2] f32 -> out [B,C,H,W] f32.
//
// v3 change: pre-transpose im0 to pixel-major [B,HW,C] in d_ws so the
// gather's scattered per-entry reads are 4x float4 from ONE 64B line
// (R2 was 16x 4B across 16 distinct lines -> TCP line-request bound).
// Gather otherwise as R2: 16x16 tile x 16 ch per block, halo scan ->
// LDS queue -> LDS-atomic accumulate -> non-atomic tile writeout.

constexpr int B = 8;
constexpr int C = 16;
constexpr int H = 512;
constexpr int W = 512;
constexpr int HW = H * W;

constexpr int T    = 16;          // output tile side
constexpr int R    = 32;          // halo radius (covers |flow| <= 30)
constexpr int HALO = T + 2 * R;   // 80
constexpr int CAP  = 768;         // queue capacity (expected ~300 entries)
constexpr int ASTR = 260;         // acc channel stride (16B aligned)
constexpr float FARTH = 30.0f;

// ---------------- transpose: im0 [B,C,HW] -> im0t [B,HW,C] ----------------
__global__ __launch_bounds__(256) void im0_transpose(
    const float* __restrict__ im0, float* __restrict__ im0t) {
  __shared__ float sbuf[C][257];          // +1 pad: conflict-free both phases
  const int blk = blockIdx.x;             // B * (HW/256) = 8192
  const int b   = blk >> 10;              // HW/256 = 1024
  const int p0  = (blk & 1023) << 8;
  const int t   = threadIdx.x;

  const float* src = im0 + (size_t)b * C * HW + p0;
  #pragma unroll
  for (int c = 0; c < C; ++c) sbuf[c][t] = src[(size_t)c * HW + t];
  __syncthreads();

  float4* dst = reinterpret_cast<float4*>(im0t + ((size_t)b * HW + p0) * C);
  #pragma unroll
  for (int it = 0; it < 4; ++it) {
    int k  = t + it * 256;                // 1024 float4 chunks = 256 pix * 16 ch
    int pk = k >> 2, q = (k & 3) * 4;
    dst[k] = make_float4(sbuf[q][pk], sbuf[q + 1][pk],
                         sbuf[q + 2][pk], sbuf[q + 3][pk]);
  }
}

// ---------------- gather ----------------
template <bool TR>
__global__ __launch_bounds__(256, 7) void fwarp_gather(
    const float* __restrict__ im0,
    const float* __restrict__ im0t,
    const float* __restrict__ flow,
    float* __restrict__ out) {

  __shared__ float acc[C * ASTR];   // 16640 B
  __shared__ int   queue[CAP];      // 3072 B
  __shared__ int   qcount;

  const int tx0 = blockIdx.x * T;
  const int ty0 = blockIdx.y * T;
  const int b   = blockIdx.z;
  const int tid = threadIdx.x;

  for (int i = tid; i < C * ASTR; i += 256) acc[i] = 0.0f;
  if (tid == 0) qcount = 0;
  __syncthreads();

  const float2* __restrict__ flowv =
      reinterpret_cast<const float2*>(flow) + (size_t)b * HW;
  const float* __restrict__ imb = im0 + (size_t)b * C * HW;

  // ---- phase 1: scan halo, compact hits into LDS queue ----
  const int hy0 = ty0 - R, wx0 = tx0 - R;
  for (int i = tid; i < HALO * HALO; i += 256) {
    int cy = i / HALO;
    int cx = i - cy * HALO;
    int hh = hy0 + cy, ww = wx0 + cx;
    if ((unsigned)hh >= (unsigned)H || (unsigned)ww >= (unsigned)W) continue;
    int p = hh * W + ww;
    float2 f = flowv[p];
    if (fabsf(f.x) > FARTH || fabsf(f.y) > FARTH) continue;  // far kernel
    float x = (float)ww + f.x;
    float y = (float)hh + f.y;
    int x0 = (int)floorf(x);
    int y0 = (int)floorf(y);
    if (x0 < tx0 - 1 || x0 > tx0 + T - 1 || y0 < ty0 - 1 || y0 > ty0 + T - 1)
      continue;
    int slot = atomicAdd(&qcount, 1);
    if (slot < CAP) {
      queue[slot] = p;
    } else {
      // overflow (never expected): accumulate into LDS acc inline.
      float x0f = floorf(x), y0f = floorf(y);
      float fx = x - x0f, fy = y - y0f;
      float w00 = (1.0f - fx) * (1.0f - fy), w01 = fx * (1.0f - fy);
      float w10 = (1.0f - fx) * fy,          w11 = fx * fy;
      int lx = x0 - tx0, ly = y0 - ty0;
      bool cx0 = (unsigned)lx < (unsigned)T, cx1 = (unsigned)(lx + 1) < (unsigned)T;
      bool cy0 = (unsigned)ly < (unsigned)T, cy1 = (unsigned)(ly + 1) < (unsigned)T;
      int base = ly * T + lx;
      for (int c = 0; c < C; ++c) {
        float v = imb[(size_t)c * HW + p];
        float* a = acc + c * ASTR;
        if (cx0 & cy0) atomicAdd(a + base,         v * w00);
        if (cx1 & cy0) atomicAdd(a + base + 1,     v * w01);
        if (cx0 & cy1) atomicAdd(a + base + T,     v * w10);
        if (cx1 & cy1) atomicAdd(a + base + T + 1, v * w11);
      }
    }
  }
  __syncthreads();

  // ---- phase 2: (entry x channel-group), 4 threads per entry ----
  const float4* __restrict__ imt4 =
      reinterpret_cast<const float4*>(im0t) + (size_t)b * HW * 4;
  int n = min(qcount, CAP);
  for (int k = tid; k < n * 4; k += 256) {
    int e  = k >> 2;
    int q  = k & 3;              // channel group index
    int cg = q * 4;              // channels cg..cg+3
    int p  = queue[e];
    int hh = p >> 9, ww = p & (W - 1);
    float2 f = flowv[p];         // L2-hot; 4 lanes same addr -> broadcast
    float x = (float)ww + f.x;
    float y = (float)hh + f.y;
    float x0f = floorf(x), y0f = floorf(y);
    float fx = x - x0f, fy = y - y0f;
    float w00 = (1.0f - fx) * (1.0f - fy), w01 = fx * (1.0f - fy);
    float w10 = (1.0f - fx) * fy,          w11 = fx * fy;
    int lx = (int)x0f - tx0, ly = (int)y0f - ty0;
    bool cx0 = (unsigned)lx < (unsigned)T, cx1 = (unsigned)(lx + 1) < (unsigned)T;
    bool cy0 = (unsigned)ly < (unsigned)T, cy1 = (unsigned)(ly + 1) < (unsigned)T;
    int base = ly * T + lx;

    float vv[4];
    if (TR) {
      float4 v4 = imt4[(size_t)p * 4 + q];   // one 16B slice of p's 64B block
      vv[0] = v4.x; vv[1] = v4.y; vv[2] = v4.z; vv[3] = v4.w;
    } else {
      const float* sp = imb + (size_t)cg * HW + p;
      #pragma unroll
      for (int c = 0; c < 4; ++c) vv[c] = sp[(size_t)c * HW];
    }

    float* a = acc + cg * ASTR + base;
    #pragma unroll
    for (int c = 0; c < 4; ++c) {
      float v = vv[c];
      float* ac = a + c * ASTR;
      if (cx0 & cy0) atomicAdd(ac,         v * w00);
      if (cx1 & cy0) atomicAdd(ac + 1,     v * w01);
      if (cx0 & cy1) atomicAdd(ac + T,     v * w10);
      if (cx1 & cy1) atomicAdd(ac + T + 1, v * w11);
    }
  }
  __syncthreads();

  // ---- phase 3: non-atomic float4 tile writeout ----
  float* ob = out + (size_t)b * C * HW + ty0 * W + tx0;
  for (int k = tid; k < C * T * T / 4; k += 256) {   // 1024 float4 stores
    int c   = k >> 6;
    int idx = k & 63;
    int r   = idx >> 2;
    int x4  = (idx & 3) * 4;
    const float* s = acc + c * ASTR + r * T + x4;
    *reinterpret_cast<float4*>(ob + (size_t)c * HW + r * W + x4) =
        make_float4(s[0], s[1], s[2], s[3]);
  }
}

// ---------------- rare far-flow path ----------------
__global__ __launch_bounds__(256) void fwarp_far(
    const float* __restrict__ im0,
    const float* __restrict__ flow,
    float* __restrict__ out) {

  int idx = blockIdx.x * blockDim.x + threadIdx.x;  // over B*H*W
  if (idx >= B * HW) return;
  float2 f = reinterpret_cast<const float2*>(flow)[idx];
  if (!(fabsf(f.x) > FARTH || fabsf(f.y) > FARTH)) return;

  int w = idx & (W - 1);
  int h = (idx >> 9) & (H - 1);
  int b = idx >> 18;

  float x = (float)w + f.x;
  float y = (float)h + f.y;
  float x0f = floorf(x), y0f = floorf(y);
  int x0 = (int)x0f, y0 = (int)y0f;
  float fx = x - x0f, fy = y - y0f;
  float w00 = (1.0f - fx) * (1.0f - fy), w01 = fx * (1.0f - fy);
  float w10 = (1.0f - fx) * fy,          w11 = fx * fy;

  bool vx0 = (unsigned)x0 < (unsigned)W;
  bool vx1 = (unsigned)(x0 + 1) < (unsigned)W;
  bool vy0 = (unsigned)y0 < (unsigned)H;
  bool vy1 = (unsigned)(y0 + 1) < (unsigned)H;
  bool p00 = vx0 && vy0, p01 = vx1 && vy0, p10 = vx0 && vy1, p11 = vx1 && vy1;
  if (!(p00 | p01 | p10 | p11)) return;

  int g00 = y0 * W + x0;
  const float* src = im0 + (size_t)b * C * HW + h * W + w;
  float* dst = out + (size_t)b * C * HW;
  for (int c = 0; c < C; ++c) {
    float v = src[(size_t)c * HW];
    float* o = dst + (size_t)c * HW;
    if (p00) atomicAdd(o + g00,         v * w00);
    if (p01) atomicAdd(o + g00 + 1,     v * w01);
    if (p10) atomicAdd(o + g00 + W,     v * w10);
    if (p11) atomicAdd(o + g00 + W + 1, v * w11);
  }
}

extern "C" void kernel_launch(void* const* d_in, const int* in_sizes, int n_in,
                              void* d_out, int out_size, void* d_ws, size_t ws_size,
                              hipStream_t stream) {
  const float* im0  = (const float*)d_in[0];
  const float* flow = (const float*)d_in[1];
  float* out = (float*)d_out;
  float* im0t = (float*)d_ws;

  const size_t need = (size_t)B * C * HW * sizeof(float);  // 128 MB
  const bool use_tr = (ws_size >= need);

  dim3 grid(W / T, H / T, B);   // 32 x 32 x 8 = 8192 blocks

  if (use_tr) {
    im0_transpose<<<B * (HW / 256), 256, 0, stream>>>(im0, im0t);
    fwarp_gather<true><<<grid, 256, 0, stream>>>(im0, im0t, flow, out);
  } else {
    fwarp_gather<false><<<grid, 256, 0, stream>>>(im0, im0, flow, out);
  }

  int blocks = (B * HW + 255) / 256;
  fwarp_far<<<blocks, 256, 0, stream>>>(im0, flow, out);
}